// Round 10
// baseline (383.977 us; speedup 1.0000x reference)
//
#include <hip/hip_runtime.h>
#include <hip/hip_fp16.h>

#define S_LEN 512
#define B_DIM 1024
#define T_DIM 48
#define L2E 1.4426950408889634f
#define LN2 0.6931471805599453f

// v_exp_f32 computes 2^x ; v_log_f32 computes log2(x)
#define EXP2F(x) __builtin_amdgcn_exp2f(x)
#define LOG2F(x) __builtin_amdgcn_logf(x)

typedef _Float16 h2v __attribute__((ext_vector_type(2)));

// packed f16 max (ROCm 7.2 lacks __hmax2): <2 x half> llvm.maxnum -> v_pk_max_f16
__device__ __forceinline__ __half2 hmax2(__half2 a, __half2 b) {
  h2v r = __builtin_elementwise_max(__builtin_bit_cast(h2v, a),
                                    __builtin_bit_cast(h2v, b));
  return __builtin_bit_cast(__half2, r);
}

// broadcast the 32-bit pair held by lane (idx/4) to all lanes via the LDS
// crossbar (ds_bpermute_b32) -- issues on the LDS pipe, not VALU.
__device__ __forceinline__ __half2 bperm(int idx, __half2 src) {
  int s = __builtin_amdgcn_ds_bpermute(idx, __builtin_bit_cast(int, src));
  return __builtin_bit_cast(__half2, s);
}

// ---- DPP wave-64 reduction helpers (full result valid in lane 63) ----
template <int CTRL, int RMASK>
__device__ __forceinline__ float dppmovf(float v) {
  return __int_as_float(__builtin_amdgcn_update_dpp(
      __float_as_int(v), __float_as_int(v), CTRL, RMASK, 0xF, false));
}
template <int CTRL, int RMASK>
__device__ __forceinline__ float dppmaxf(float m) {
  return fmaxf(m, dppmovf<CTRL, RMASK>(m));
}
template <int CTRL, int RMASK>
__device__ __forceinline__ float dppaddf(float m) {
  return m + dppmovf<CTRL, RMASK>(m);
}

__device__ __forceinline__ float wave_max63(float m) {
  m = dppmaxf<0xB1, 0xF>(m);   // xor 1
  m = dppmaxf<0x4E, 0xF>(m);   // xor 2
  m = dppmaxf<0x141, 0xF>(m);  // xor 4 (row_half_mirror)
  m = dppmaxf<0x140, 0xF>(m);  // xor 8 (row_mirror)
  m = dppmaxf<0x142, 0xA>(m);  // row_bcast15 -> rows 1,3
  m = dppmaxf<0x143, 0xC>(m);  // row_bcast31 -> rows 2,3 ; lane63 = full max
  return __int_as_float(__builtin_amdgcn_readlane(__float_as_int(m), 63));
}
__device__ __forceinline__ float wave_sum63(float m) {
  m = dppaddf<0xB1, 0xF>(m);
  m = dppaddf<0x4E, 0xF>(m);
  m = dppaddf<0x141, 0xF>(m);
  m = dppaddf<0x140, 0xF>(m);
  m = dppaddf<0x142, 0xA>(m);
  m = dppaddf<0x143, 0xC>(m);
  return __int_as_float(__builtin_amdgcn_readlane(__float_as_int(m), 63));
}

// ---- main scan: blocks 0..1023 = forward(LSE) chain, 1024..2047 = viterbi(max).
// One wave per chain; lane = tag index, lanes >= 48 clone lane 47.
// Broadcast of the 48-state vector: DPP quad-swap packs (x_i, x_{i^1}) into an
// f16 pair per even lane; 24 ds_bpermute broadcasts (LDS pipe) feed packed
// __half2 math (v_pk_fma / v_pk_add / v_pk_max). No barriers.
__global__ __launch_bounds__(64)
void crf_scan(const float* __restrict__ em, const float* __restrict__ mask,
              const float* __restrict__ trans, const float* __restrict__ startT,
              const float* __restrict__ stopT, float* __restrict__ out)
{
  const int b    = blockIdx.x & (B_DIM - 1);
  const int mode = blockIdx.x >> 10;   // 0 = fv, 1 = vv
  const int i    = threadIdx.x;
  const int ri   = (i < T_DIM) ? i : (T_DIM - 1);

  float v = startT[ri] + em[(size_t)b * T_DIM + ri];

  const float* emb = em + (size_t)b * T_DIM + ri;
  const size_t estep = (size_t)B_DIM * T_DIM;
  float e1 = emb[1 * estep];
  float e2 = emb[2 * estep];
  float e3 = emb[3 * estep];
  float mk = mask[B_DIM + b];

  // pinned uniform bpermute indices (byte addr of even lane 2k), kept in VGPRs
  int bidx[24];
#pragma unroll
  for (int k = 0; k < 24; ++k) {
    bidx[k] = 8 * k;
    asm("" : "+v"(bidx[k]));   // opaque: prevent rematerialization in-loop
  }

  if (mode == 0) {
    // per-lane row ri of exp(trans), f16 RNE packed over j-pairs
    __half2 Epk[24];
#pragma unroll
    for (int k = 0; k < 24; ++k)
      Epk[k] = __floats2half2_rn(EXP2F(trans[ri * T_DIM + 2 * k]     * L2E),
                                 EXP2F(trans[ri * T_DIM + 2 * k + 1] * L2E));

#pragma unroll 2
    for (int s = 1; s < S_LEN; ++s) {
      int sp = (s + 3 < S_LEN) ? s + 3 : S_LEN - 1;
      float ep  = emb[(size_t)sp * estep];
      int sn = (s + 1 < S_LEN) ? s + 1 : S_LEN - 1;
      float mkn = mask[sn * B_DIM + b];

      float mf = wave_max63(v);                      // exp stability (p <= 1)
      float p  = EXP2F((v - mf) * L2E);
      float pn = dppmovf<0xB1, 0xF>(p);              // neighbor (i^1)
      __half2 pp = __floats2half2_rn(p, pn);         // even lane 2k: (p_2k, p_2k+1)

      __half2 a0 = __float2half2_rn(0.f), a1 = a0, a2 = a0, a3 = a0;
#pragma unroll
      for (int k = 0; k < 6; ++k) {
        a0 = __hfma2(bperm(bidx[k],      pp), Epk[k],      a0);
        a1 = __hfma2(bperm(bidx[k + 6],  pp), Epk[k + 6],  a1);
        a2 = __hfma2(bperm(bidx[k + 12], pp), Epk[k + 12], a2);
        a3 = __hfma2(bperm(bidx[k + 18], pp), Epk[k + 18], a3);
      }
      a0 = __hadd2(a0, a1); a2 = __hadd2(a2, a3); a0 = __hadd2(a0, a2);
      float accF = __low2float(a0) + __high2float(a0);  // sum_j p_j*exp(t_ij)

      // new_fv = em + mf + ln(accF), absolute coordinates
      float fnew = fmaf(LN2, LOG2F(fmaxf(accF, 1e-30f)), e1 + mf);
      v = fmaf(mk, fnew - v, v);                     // mask blend

      e1 = e2; e2 = e3; e3 = ep; mk = mkn;
    }
    float q  = v + stopT[ri];
    float mq = wave_max63(q);
    float e  = EXP2F((q - mq) * L2E);
    e = (i < T_DIM) ? e : 0.f;                       // zero clone lanes
    float alpha = mq + LN2 * LOG2F(wave_sum63(e));
    if (i == 0) out[1 + B_DIM + b] = alpha;
  } else {
    __half2 Tpk[24];
#pragma unroll
    for (int k = 0; k < 24; ++k)
      Tpk[k] = __floats2half2_rn(trans[ri * T_DIM + 2 * k],
                                 trans[ri * T_DIM + 2 * k + 1]);

    // stale-max rebase: exact wave max every 8 steps; between resyncs
    // |v - m_ref| stays well inside f16 range (worst-case drift ~14/step).
    float m_ref = wave_max63(v);
    const __half2 NEG = __floats2half2_rn(-60000.f, -60000.f);

#pragma unroll 8
    for (int s = 1; s < S_LEN; ++s) {
      int sp = (s + 3 < S_LEN) ? s + 3 : S_LEN - 1;
      float ep  = emb[(size_t)sp * estep];
      int sn = (s + 1 < S_LEN) ? s + 1 : S_LEN - 1;
      float mkn = mask[sn * B_DIM + b];

      if ((s & 7) == 0) m_ref = wave_max63(v);       // compile-time per unroll pos
      float vr = v - m_ref;                          // f16-safe magnitude
      float vn_ = dppmovf<0xB1, 0xF>(vr);
      __half2 vp = __floats2half2_rn(vr, vn_);       // even lane 2k: (vr_2k, vr_2k+1)

      __half2 m0 = NEG, m1 = NEG;
#pragma unroll
      for (int k = 0; k < 12; ++k) {
        m0 = hmax2(m0, __hadd2(bperm(bidx[k],      vp), Tpk[k]));
        m1 = hmax2(m1, __hadd2(bperm(bidx[k + 12], vp), Tpk[k + 12]));
      }
      m0 = hmax2(m0, m1);
      float mx = fmaxf(__low2float(m0), __high2float(m0));  // max_j(vr_j+t_ij)

      float vnew = e1 + m_ref + mx;                  // back to absolute coords
      v = fmaf(mk, vnew - v, v);                     // mask blend

      e1 = e2; e2 = e3; e3 = ep; mk = mkn;
    }
    float best = wave_max63(v + stopT[ri]);
    if (i == 0) out[1 + 2 * B_DIM + b] = best;
  }
}

// ---- real-path score: one block per b, deterministic LDS tree reduction ----
__global__ __launch_bounds__(256)
void crf_real(const float* __restrict__ em, const int* __restrict__ tags,
              const float* __restrict__ mask, const float* __restrict__ trans,
              const float* __restrict__ startT, const float* __restrict__ stopT,
              float* __restrict__ out)
{
  __shared__ float red[256];
  const int b = blockIdx.x;
  const int t = threadIdx.x;
  float acc = 0.f;
  for (int s = 1 + t; s < S_LEN; s += 256) {
    int   tp  = tags[(s - 1) * B_DIM + b];
    int   tc  = tags[s * B_DIM + b];
    float mkv = mask[s * B_DIM + b];
    float emt = em[((size_t)s * B_DIM + b) * T_DIM + tc];
    acc = fmaf(mkv, trans[tp * T_DIM + tc] + emt, acc);
  }
  red[t] = acc;
  __syncthreads();
  for (int w = 128; w > 0; w >>= 1) {
    if (t < w) red[t] += red[t + w];
    __syncthreads();
  }
  if (t == 0)
    out[1 + b] = startT[tags[b]] + stopT[tags[(S_LEN - 1) * B_DIM + b]] + red[0];
}

// ---- loss = mean(alpha - real) ----
__global__ __launch_bounds__(256)
void crf_loss(float* __restrict__ out)
{
  __shared__ float red[256];
  int t = threadIdx.x;
  float a = 0.f;
  for (int b = t; b < B_DIM; b += 256)
    a += out[1 + B_DIM + b] - out[1 + b];
  red[t] = a;
  __syncthreads();
  for (int w = 128; w > 0; w >>= 1) {
    if (t < w) red[t] += red[t + w];
    __syncthreads();
  }
  if (t == 0) out[0] = red[0] * (1.0f / B_DIM);
}

extern "C" void kernel_launch(void* const* d_in, const int* in_sizes, int n_in,
                              void* d_out, int out_size, void* d_ws, size_t ws_size,
                              hipStream_t stream) {
  (void)in_sizes; (void)n_in; (void)d_ws; (void)ws_size; (void)out_size;
  const float* em     = (const float*)d_in[0];
  const int*   tags   = (const int*)d_in[1];
  const float* mask   = (const float*)d_in[2];
  const float* trans  = (const float*)d_in[3];
  const float* startT = (const float*)d_in[4];
  const float* stopT  = (const float*)d_in[5];
  float* out = (float*)d_out;

  hipLaunchKernelGGL(crf_scan, dim3(2 * B_DIM), dim3(64), 0, stream,
                     em, mask, trans, startT, stopT, out);
  hipLaunchKernelGGL(crf_real, dim3(B_DIM), dim3(256), 0, stream,
                     em, tags, mask, trans, startT, stopT, out);
  hipLaunchKernelGGL(crf_loss, dim3(1), dim3(256), 0, stream, out);
}

// Round 11
// 279.486 us; speedup vs baseline: 1.3739x; 1.3739x over previous
//
#include <hip/hip_runtime.h>
#include <hip/hip_fp16.h>

#define S_LEN 512
#define B_DIM 1024
#define T_DIM 48
#define L2E 1.4426950408889634f
#define LN2 0.6931471805599453f

// v_exp_f32 computes 2^x ; v_log_f32 computes log2(x)
#define EXP2F(x) __builtin_amdgcn_exp2f(x)
#define LOG2F(x) __builtin_amdgcn_logf(x)

typedef _Float16 h2v __attribute__((ext_vector_type(2)));

// packed f16 max (ROCm 7.2 lacks __hmax2): <2 x half> llvm.maxnum -> v_pk_max_f16
__device__ __forceinline__ __half2 hmax2(__half2 a, __half2 b) {
  h2v r = __builtin_elementwise_max(__builtin_bit_cast(h2v, a),
                                    __builtin_bit_cast(h2v, b));
  return __builtin_bit_cast(__half2, r);
}

// broadcast the 32-bit pair held by `lane` to all lanes (readlane -> SGPR)
__device__ __forceinline__ __half2 bpick(__half2 src, int lane) {
  int s = __builtin_amdgcn_readlane(__builtin_bit_cast(int, src), lane);
  return __builtin_bit_cast(__half2, s);
}

// ---- DPP wave-64 reduction helpers (full result valid in lane 63) ----
template <int CTRL, int RMASK>
__device__ __forceinline__ float dppmovf(float v) {
  return __int_as_float(__builtin_amdgcn_update_dpp(
      __float_as_int(v), __float_as_int(v), CTRL, RMASK, 0xF, false));
}
template <int CTRL, int RMASK>
__device__ __forceinline__ float dppmaxf(float m) {
  return fmaxf(m, dppmovf<CTRL, RMASK>(m));
}
template <int CTRL, int RMASK>
__device__ __forceinline__ float dppaddf(float m) {
  return m + dppmovf<CTRL, RMASK>(m);
}

__device__ __forceinline__ float wave_max63(float m) {
  m = dppmaxf<0xB1, 0xF>(m);   // xor 1
  m = dppmaxf<0x4E, 0xF>(m);   // xor 2
  m = dppmaxf<0x141, 0xF>(m);  // xor 4 (row_half_mirror)
  m = dppmaxf<0x140, 0xF>(m);  // xor 8 (row_mirror)
  m = dppmaxf<0x142, 0xA>(m);  // row_bcast15 -> rows 1,3
  m = dppmaxf<0x143, 0xC>(m);  // row_bcast31 -> rows 2,3 ; lane63 = full max
  return __int_as_float(__builtin_amdgcn_readlane(__float_as_int(m), 63));
}
__device__ __forceinline__ float wave_sum63(float m) {
  m = dppaddf<0xB1, 0xF>(m);
  m = dppaddf<0x4E, 0xF>(m);
  m = dppaddf<0x141, 0xF>(m);
  m = dppaddf<0x140, 0xF>(m);
  m = dppaddf<0x142, 0xA>(m);
  m = dppaddf<0x143, 0xC>(m);
  return __int_as_float(__builtin_amdgcn_readlane(__float_as_int(m), 63));
}

// ---- main scan, 2 chains per wave: f16 halves = (batch bA, batch bB).
// Blocks 0..511 = forward(LSE) pairs, 512..1023 = viterbi(max) pairs.
// Lane j owns tag j for both chains (lanes >= 48 clone lane 47); one
// v_readlane broadcasts (xA_j, xB_j); one v_pk_* advances both chains.
__global__ __launch_bounds__(64)
void crf_scan(const float* __restrict__ em, const float* __restrict__ mask,
              const float* __restrict__ trans, const float* __restrict__ startT,
              const float* __restrict__ stopT, float* __restrict__ out)
{
  const int pb   = blockIdx.x & 511;
  const int mode = blockIdx.x >> 9;    // 0 = fv, 1 = vv (pb and pb+512 same XCD)
  const int bA   = 2 * pb;
  const int bB   = 2 * pb + 1;
  const int i    = threadIdx.x;
  const int ri   = (i < T_DIM) ? i : (T_DIM - 1);

  float vA = startT[ri] + em[(size_t)bA * T_DIM + ri];
  float vB = startT[ri] + em[(size_t)bB * T_DIM + ri];

  const float* emA = em + (size_t)bA * T_DIM + ri;
  const float* emB = em + (size_t)bB * T_DIM + ri;
  const size_t estep = (size_t)B_DIM * T_DIM;
  float e1A = emA[1 * estep], e2A = emA[2 * estep], e3A = emA[3 * estep];
  float e1B = emB[1 * estep], e2B = emB[2 * estep], e3B = emB[3 * estep];
  float mkA = mask[B_DIM + bA];
  float mkB = mask[B_DIM + bB];

  if (mode == 0) {
    // row ri of exp(trans), duplicated into both f16 halves
    __half2 EEd[T_DIM];
#pragma unroll
    for (int k = 0; k < T_DIM; ++k) {
      float e = EXP2F(trans[ri * T_DIM + k] * L2E);
      EEd[k] = __floats2half2_rn(e, e);
    }

    for (int s = 1; s < S_LEN; ++s) {
      int sp = (s + 3 < S_LEN) ? s + 3 : S_LEN - 1;
      float epA = emA[(size_t)sp * estep];
      float epB = emB[(size_t)sp * estep];
      int sn = (s + 1 < S_LEN) ? s + 1 : S_LEN - 1;
      float mknA = mask[sn * B_DIM + bA];
      float mknB = mask[sn * B_DIM + bB];

      float mfA = wave_max63(vA);                    // two independent trees
      float mfB = wave_max63(vB);                    // interleave in the pipe
      float pA  = EXP2F((vA - mfA) * L2E);           // in [0,1]
      float pB  = EXP2F((vB - mfB) * L2E);
      __half2 pp = __floats2half2_rn(pA, pB);        // lane j: (pA_j, pB_j)

      __half2 a0 = __float2half2_rn(0.f), a1 = a0, a2 = a0, a3 = a0;
#pragma unroll
      for (int k = 0; k < 12; ++k) {                 // 48 j's, 4 indep chains
        a0 = __hfma2(bpick(pp, 4 * k + 0), EEd[4 * k + 0], a0);
        a1 = __hfma2(bpick(pp, 4 * k + 1), EEd[4 * k + 1], a1);
        a2 = __hfma2(bpick(pp, 4 * k + 2), EEd[4 * k + 2], a2);
        a3 = __hfma2(bpick(pp, 4 * k + 3), EEd[4 * k + 3], a3);
      }
      __half2 at = __hadd2(__hadd2(a0, a1), __hadd2(a2, a3));
      float accA = __low2float(at);                  // sum_j pA_j * exp(t_ij)
      float accB = __high2float(at);

      float fnA = fmaf(LN2, LOG2F(fmaxf(accA, 1e-30f)), e1A + mfA);
      float fnB = fmaf(LN2, LOG2F(fmaxf(accB, 1e-30f)), e1B + mfB);
      vA = fmaf(mkA, fnA - vA, vA);
      vB = fmaf(mkB, fnB - vB, vB);

      e1A = e2A; e2A = e3A; e3A = epA; mkA = mknA;
      e1B = e2B; e2B = e3B; e3B = epB; mkB = mknB;
    }
    float qA  = vA + stopT[ri];
    float qB  = vB + stopT[ri];
    float mqA = wave_max63(qA);
    float mqB = wave_max63(qB);
    float eA  = EXP2F((qA - mqA) * L2E);
    float eB  = EXP2F((qB - mqB) * L2E);
    eA = (i < T_DIM) ? eA : 0.f;                     // zero clone lanes
    eB = (i < T_DIM) ? eB : 0.f;
    float alA = mqA + LN2 * LOG2F(wave_sum63(eA));
    float alB = mqB + LN2 * LOG2F(wave_sum63(eB));
    if (i == 0) {
      out[1 + B_DIM + bA] = alA;
      out[1 + B_DIM + bB] = alB;
    }
  } else {
    __half2 TTd[T_DIM];
#pragma unroll
    for (int k = 0; k < T_DIM; ++k) {
      float t = trans[ri * T_DIM + k];
      TTd[k] = __floats2half2_rn(t, t);
    }
    const __half2 NEG = __floats2half2_rn(-60000.f, -60000.f);

    for (int s = 1; s < S_LEN; ++s) {
      int sp = (s + 3 < S_LEN) ? s + 3 : S_LEN - 1;
      float epA = emA[(size_t)sp * estep];
      float epB = emB[(size_t)sp * estep];
      int sn = (s + 1 < S_LEN) ? s + 1 : S_LEN - 1;
      float mknA = mask[sn * B_DIM + bA];
      float mknB = mask[sn * B_DIM + bB];

      float mvA = wave_max63(vA);
      float mvB = wave_max63(vB);
      float vrA = vA - mvA;                          // <= 0, f16-safe
      float vrB = vB - mvB;
      __half2 vp = __floats2half2_rn(vrA, vrB);      // lane j: (vrA_j, vrB_j)

      __half2 m0 = NEG, m1 = NEG, m2 = NEG, m3 = NEG;
#pragma unroll
      for (int k = 0; k < 12; ++k) {
        m0 = hmax2(m0, __hadd2(bpick(vp, 4 * k + 0), TTd[4 * k + 0]));
        m1 = hmax2(m1, __hadd2(bpick(vp, 4 * k + 1), TTd[4 * k + 1]));
        m2 = hmax2(m2, __hadd2(bpick(vp, 4 * k + 2), TTd[4 * k + 2]));
        m3 = hmax2(m3, __hadd2(bpick(vp, 4 * k + 3), TTd[4 * k + 3]));
      }
      __half2 mm = hmax2(hmax2(m0, m1), hmax2(m2, m3));
      float mxA = __low2float(mm);                   // max_j (vrA_j + t_ij)
      float mxB = __high2float(mm);

      float vnA = e1A + mvA + mxA;
      float vnB = e1B + mvB + mxB;
      vA = fmaf(mkA, vnA - vA, vA);
      vB = fmaf(mkB, vnB - vB, vB);

      e1A = e2A; e2A = e3A; e3A = epA; mkA = mknA;
      e1B = e2B; e2B = e3B; e3B = epB; mkB = mknB;
    }
    float bstA = wave_max63(vA + stopT[ri]);
    float bstB = wave_max63(vB + stopT[ri]);
    if (i == 0) {
      out[1 + 2 * B_DIM + bA] = bstA;
      out[1 + 2 * B_DIM + bB] = bstB;
    }
  }
}

// ---- real-path score: one block per b, deterministic LDS tree reduction ----
__global__ __launch_bounds__(256)
void crf_real(const float* __restrict__ em, const int* __restrict__ tags,
              const float* __restrict__ mask, const float* __restrict__ trans,
              const float* __restrict__ startT, const float* __restrict__ stopT,
              float* __restrict__ out)
{
  __shared__ float red[256];
  const int b = blockIdx.x;
  const int t = threadIdx.x;
  float acc = 0.f;
  for (int s = 1 + t; s < S_LEN; s += 256) {
    int   tp  = tags[(s - 1) * B_DIM + b];
    int   tc  = tags[s * B_DIM + b];
    float mkv = mask[s * B_DIM + b];
    float emt = em[((size_t)s * B_DIM + b) * T_DIM + tc];
    acc = fmaf(mkv, trans[tp * T_DIM + tc] + emt, acc);
  }
  red[t] = acc;
  __syncthreads();
  for (int w = 128; w > 0; w >>= 1) {
    if (t < w) red[t] += red[t + w];
    __syncthreads();
  }
  if (t == 0)
    out[1 + b] = startT[tags[b]] + stopT[tags[(S_LEN - 1) * B_DIM + b]] + red[0];
}

// ---- loss = mean(alpha - real) ----
__global__ __launch_bounds__(256)
void crf_loss(float* __restrict__ out)
{
  __shared__ float red[256];
  int t = threadIdx.x;
  float a = 0.f;
  for (int b = t; b < B_DIM; b += 256)
    a += out[1 + B_DIM + b] - out[1 + b];
  red[t] = a;
  __syncthreads();
  for (int w = 128; w > 0; w >>= 1) {
    if (t < w) red[t] += red[t + w];
    __syncthreads();
  }
  if (t == 0) out[0] = red[0] * (1.0f / B_DIM);
}

extern "C" void kernel_launch(void* const* d_in, const int* in_sizes, int n_in,
                              void* d_out, int out_size, void* d_ws, size_t ws_size,
                              hipStream_t stream) {
  (void)in_sizes; (void)n_in; (void)d_ws; (void)ws_size; (void)out_size;
  const float* em     = (const float*)d_in[0];
  const int*   tags   = (const int*)d_in[1];
  const float* mask   = (const float*)d_in[2];
  const float* trans  = (const float*)d_in[3];
  const float* startT = (const float*)d_in[4];
  const float* stopT  = (const float*)d_in[5];
  float* out = (float*)d_out;

  hipLaunchKernelGGL(crf_scan, dim3(B_DIM), dim3(64), 0, stream,
                     em, mask, trans, startT, stopT, out);
  hipLaunchKernelGGL(crf_real, dim3(B_DIM), dim3(256), 0, stream,
                     em, tags, mask, trans, startT, stopT, out);
  hipLaunchKernelGGL(crf_loss, dim3(1), dim3(256), 0, stream, out);
}

// Round 12
// 226.796 us; speedup vs baseline: 1.6931x; 1.2323x over previous
//
#include <hip/hip_runtime.h>
#include <hip/hip_fp16.h>

#define S_LEN 512
#define B_DIM 1024
#define T_DIM 48
#define L2E 1.4426950408889634f
#define LN2 0.6931471805599453f

// v_exp_f32 computes 2^x ; v_log_f32 computes log2(x)
#define EXP2F(x) __builtin_amdgcn_exp2f(x)
#define LOG2F(x) __builtin_amdgcn_logf(x)

typedef _Float16 h2v __attribute__((ext_vector_type(2)));

// packed f16 max (ROCm 7.2 lacks __hmax2): <2 x half> llvm.maxnum -> v_pk_max_f16
__device__ __forceinline__ __half2 hmax2(__half2 a, __half2 b) {
  h2v r = __builtin_elementwise_max(__builtin_bit_cast(h2v, a),
                                    __builtin_bit_cast(h2v, b));
  return __builtin_bit_cast(__half2, r);
}

// broadcast the 32-bit pair held by `lane` to all lanes (readlane -> SGPR)
__device__ __forceinline__ __half2 bpick(__half2 src, int lane) {
  int s = __builtin_amdgcn_readlane(__builtin_bit_cast(int, src), lane);
  return __builtin_bit_cast(__half2, s);
}

// ---- DPP wave-64 reduction helpers (full result valid in lane 63) ----
template <int CTRL, int RMASK>
__device__ __forceinline__ float dppmovf(float v) {
  return __int_as_float(__builtin_amdgcn_update_dpp(
      __float_as_int(v), __float_as_int(v), CTRL, RMASK, 0xF, false));
}
template <int CTRL, int RMASK>
__device__ __forceinline__ float dppmaxf(float m) {
  return fmaxf(m, dppmovf<CTRL, RMASK>(m));
}
template <int CTRL, int RMASK>
__device__ __forceinline__ float dppaddf(float m) {
  return m + dppmovf<CTRL, RMASK>(m);
}

__device__ __forceinline__ float wave_max63(float m) {
  m = dppmaxf<0xB1, 0xF>(m);   // xor 1
  m = dppmaxf<0x4E, 0xF>(m);   // xor 2
  m = dppmaxf<0x141, 0xF>(m);  // xor 4 (row_half_mirror)
  m = dppmaxf<0x140, 0xF>(m);  // xor 8 (row_mirror)
  m = dppmaxf<0x142, 0xA>(m);  // row_bcast15 -> rows 1,3
  m = dppmaxf<0x143, 0xC>(m);  // row_bcast31 -> rows 2,3 ; lane63 = full max
  return __int_as_float(__builtin_amdgcn_readlane(__float_as_int(m), 63));
}
__device__ __forceinline__ float wave_sum63(float m) {
  m = dppaddf<0xB1, 0xF>(m);
  m = dppaddf<0x4E, 0xF>(m);
  m = dppaddf<0x141, 0xF>(m);
  m = dppaddf<0x140, 0xF>(m);
  m = dppaddf<0x142, 0xA>(m);
  m = dppaddf<0x143, 0xC>(m);
  return __int_as_float(__builtin_amdgcn_readlane(__float_as_int(m), 63));
}

// ---- main scan: blocks 0..1023 = forward(LSE) chain, 1024..2047 = viterbi(max).
// One wave per chain; lane = tag index, lanes >= 48 clone lane 47.
// Broadcasts: DPP quad-swap packs (x_i, x_{i^1}) per even lane; v_readlane
// broadcasts issued in BATCHES OF SIX simultaneously-live temps so the
// register allocator must use >=6 distinct SGPRs -- the VALU->SGPR->VALU
// read hazard of each readlane is then covered by the other 5 (no nop
// padding, no single-SGPR false dependency chain).
__global__ __launch_bounds__(64)
void crf_scan(const float* __restrict__ em, const float* __restrict__ mask,
              const float* __restrict__ trans, const float* __restrict__ startT,
              const float* __restrict__ stopT, float* __restrict__ out)
{
  const int b    = blockIdx.x & (B_DIM - 1);
  const int mode = blockIdx.x >> 10;   // 0 = fv, 1 = vv
  const int i    = threadIdx.x;
  const int ri   = (i < T_DIM) ? i : (T_DIM - 1);

  float v = startT[ri] + em[(size_t)b * T_DIM + ri];

  const float* emb = em + (size_t)b * T_DIM + ri;
  const size_t estep = (size_t)B_DIM * T_DIM;
  float e1 = emb[1 * estep];
  float e2 = emb[2 * estep];
  float e3 = emb[3 * estep];
  float mk = mask[B_DIM + b];

  if (mode == 0) {
    // per-lane row ri of exp(trans), f16 RNE packed over j-pairs
    __half2 Epk[24];
#pragma unroll
    for (int k = 0; k < 24; ++k)
      Epk[k] = __floats2half2_rn(EXP2F(trans[ri * T_DIM + 2 * k]     * L2E),
                                 EXP2F(trans[ri * T_DIM + 2 * k + 1] * L2E));

    for (int s = 1; s < S_LEN; ++s) {
      int sp = (s + 3 < S_LEN) ? s + 3 : S_LEN - 1;
      float ep  = emb[(size_t)sp * estep];
      int sn = (s + 1 < S_LEN) ? s + 1 : S_LEN - 1;
      float mkn = mask[sn * B_DIM + b];

      float mf = wave_max63(v);                      // exp stability (p <= 1)
      float p  = EXP2F((v - mf) * L2E);
      float pn = dppmovf<0xB1, 0xF>(p);              // neighbor (i^1)
      __half2 pp = __floats2half2_rn(p, pn);         // even lane 2k: (p_2k, p_2k+1)

      __half2 a0 = __float2half2_rn(0.f), a1 = a0, a2 = a0, a3 = a0;
#pragma unroll
      for (int g = 0; g < 4; ++g) {
        // batch of 6 broadcasts -> 6 live SGPRs -> hazards overlap
        __half2 t0 = bpick(pp, 12 * g + 0);
        __half2 t1 = bpick(pp, 12 * g + 2);
        __half2 t2 = bpick(pp, 12 * g + 4);
        __half2 t3 = bpick(pp, 12 * g + 6);
        __half2 t4 = bpick(pp, 12 * g + 8);
        __half2 t5 = bpick(pp, 12 * g + 10);
        a0 = __hfma2(t0, Epk[6 * g + 0], a0);
        a1 = __hfma2(t1, Epk[6 * g + 1], a1);
        a2 = __hfma2(t2, Epk[6 * g + 2], a2);
        a3 = __hfma2(t3, Epk[6 * g + 3], a3);
        a0 = __hfma2(t4, Epk[6 * g + 4], a0);
        a1 = __hfma2(t5, Epk[6 * g + 5], a1);
      }
      a0 = __hadd2(a0, a1); a2 = __hadd2(a2, a3); a0 = __hadd2(a0, a2);
      float accF = __low2float(a0) + __high2float(a0);  // sum_j p_j*exp(t_ij)

      // new_fv = em + mf + ln(accF), absolute coordinates
      float fnew = fmaf(LN2, LOG2F(fmaxf(accF, 1e-30f)), e1 + mf);
      v = fmaf(mk, fnew - v, v);                     // mask blend

      e1 = e2; e2 = e3; e3 = ep; mk = mkn;
    }
    float q  = v + stopT[ri];
    float mq = wave_max63(q);
    float e  = EXP2F((q - mq) * L2E);
    e = (i < T_DIM) ? e : 0.f;                       // zero clone lanes
    float alpha = mq + LN2 * LOG2F(wave_sum63(e));
    if (i == 0) out[1 + B_DIM + b] = alpha;
  } else {
    __half2 Tpk[24];
#pragma unroll
    for (int k = 0; k < 24; ++k)
      Tpk[k] = __floats2half2_rn(trans[ri * T_DIM + 2 * k],
                                 trans[ri * T_DIM + 2 * k + 1]);

    // stale-max rebase: exact wave max every 8 steps (passed at absmax 8)
    float m_ref = wave_max63(v);
    const __half2 NEG = __floats2half2_rn(-60000.f, -60000.f);

#pragma unroll 8
    for (int s = 1; s < S_LEN; ++s) {
      int sp = (s + 3 < S_LEN) ? s + 3 : S_LEN - 1;
      float ep  = emb[(size_t)sp * estep];
      int sn = (s + 1 < S_LEN) ? s + 1 : S_LEN - 1;
      float mkn = mask[sn * B_DIM + b];

      if ((s & 7) == 0) m_ref = wave_max63(v);       // compile-time per unroll pos
      float vr = v - m_ref;                          // f16-safe magnitude
      float vn_ = dppmovf<0xB1, 0xF>(vr);
      __half2 vp = __floats2half2_rn(vr, vn_);       // even lane 2k: (vr_2k, vr_2k+1)

      __half2 m0 = NEG, m1 = NEG, m2 = NEG, m3 = NEG;
#pragma unroll
      for (int g = 0; g < 4; ++g) {
        __half2 t0 = bpick(vp, 12 * g + 0);
        __half2 t1 = bpick(vp, 12 * g + 2);
        __half2 t2 = bpick(vp, 12 * g + 4);
        __half2 t3 = bpick(vp, 12 * g + 6);
        __half2 t4 = bpick(vp, 12 * g + 8);
        __half2 t5 = bpick(vp, 12 * g + 10);
        m0 = hmax2(m0, __hadd2(t0, Tpk[6 * g + 0]));
        m1 = hmax2(m1, __hadd2(t1, Tpk[6 * g + 1]));
        m2 = hmax2(m2, __hadd2(t2, Tpk[6 * g + 2]));
        m3 = hmax2(m3, __hadd2(t3, Tpk[6 * g + 3]));
        m0 = hmax2(m0, __hadd2(t4, Tpk[6 * g + 4]));
        m1 = hmax2(m1, __hadd2(t5, Tpk[6 * g + 5]));
      }
      m0 = hmax2(hmax2(m0, m1), hmax2(m2, m3));
      float mx = fmaxf(__low2float(m0), __high2float(m0));  // max_j(vr_j+t_ij)

      float vnew = e1 + m_ref + mx;                  // back to absolute coords
      v = fmaf(mk, vnew - v, v);                     // mask blend

      e1 = e2; e2 = e3; e3 = ep; mk = mkn;
    }
    float best = wave_max63(v + stopT[ri]);
    if (i == 0) out[1 + 2 * B_DIM + b] = best;
  }
}

// ---- real-path score: one block per b, deterministic LDS tree reduction ----
__global__ __launch_bounds__(256)
void crf_real(const float* __restrict__ em, const int* __restrict__ tags,
              const float* __restrict__ mask, const float* __restrict__ trans,
              const float* __restrict__ startT, const float* __restrict__ stopT,
              float* __restrict__ out)
{
  __shared__ float red[256];
  const int b = blockIdx.x;
  const int t = threadIdx.x;
  float acc = 0.f;
  for (int s = 1 + t; s < S_LEN; s += 256) {
    int   tp  = tags[(s - 1) * B_DIM + b];
    int   tc  = tags[s * B_DIM + b];
    float mkv = mask[s * B_DIM + b];
    float emt = em[((size_t)s * B_DIM + b) * T_DIM + tc];
    acc = fmaf(mkv, trans[tp * T_DIM + tc] + emt, acc);
  }
  red[t] = acc;
  __syncthreads();
  for (int w = 128; w > 0; w >>= 1) {
    if (t < w) red[t] += red[t + w];
    __syncthreads();
  }
  if (t == 0)
    out[1 + b] = startT[tags[b]] + stopT[tags[(S_LEN - 1) * B_DIM + b]] + red[0];
}

// ---- loss = mean(alpha - real) ----
__global__ __launch_bounds__(256)
void crf_loss(float* __restrict__ out)
{
  __shared__ float red[256];
  int t = threadIdx.x;
  float a = 0.f;
  for (int b = t; b < B_DIM; b += 256)
    a += out[1 + B_DIM + b] - out[1 + b];
  red[t] = a;
  __syncthreads();
  for (int w = 128; w > 0; w >>= 1) {
    if (t < w) red[t] += red[t + w];
    __syncthreads();
  }
  if (t == 0) out[0] = red[0] * (1.0f / B_DIM);
}

extern "C" void kernel_launch(void* const* d_in, const int* in_sizes, int n_in,
                              void* d_out, int out_size, void* d_ws, size_t ws_size,
                              hipStream_t stream) {
  (void)in_sizes; (void)n_in; (void)d_ws; (void)ws_size; (void)out_size;
  const float* em     = (const float*)d_in[0];
  const int*   tags   = (const int*)d_in[1];
  const float* mask   = (const float*)d_in[2];
  const float* trans  = (const float*)d_in[3];
  const float* startT = (const float*)d_in[4];
  const float* stopT  = (const float*)d_in[5];
  float* out = (float*)d_out;

  hipLaunchKernelGGL(crf_scan, dim3(2 * B_DIM), dim3(64), 0, stream,
                     em, mask, trans, startT, stopT, out);
  hipLaunchKernelGGL(crf_real, dim3(B_DIM), dim3(256), 0, stream,
                     em, tags, mask, trans, startT, stopT, out);
  hipLaunchKernelGGL(crf_loss, dim3(1), dim3(256), 0, stream, out);
}